// Round 2
// baseline (996.315 us; speedup 1.0000x reference)
//
#include <hip/hip_runtime.h>

// Truncated E-step, restructured (round 2):
//   z_k = x . w[u_k] + b[u_k]  (w = mu*exp(-lnv), b = logprop - 0.5*mu'*iv*mu)
//   noise logit == NOISE_LOG_PROP by softmax shift-invariance.
// Pipeline: prep (w,b, zero out) -> resp kernel (softmax resp -> ws)
//           -> scatter kernel (LDS privatized stats, native ds_add_f32).
// KEY FIX vs round 1: unsafeAtomicAdd -> native ds_add_f32 (round 1's plain
// atomicAdd on LDS f32 compiled to a CAS loop = ~250 serial cycles/atomic,
// which explains 884us with all pipes idle).

#define UNITS 256
#define D 128
#define KCAND 10
#define NOISE_LOGIT (-2.0f)
#define HD 64              // dims per scatter half-block
#define ST 65              // LDS tile row stride (64 dims + count col)

template <int CTRL>
__device__ __forceinline__ float dpp_add(float v) {
  // quad_perm lane-xor add: 0xB1 -> xor1, 0x4E -> xor2
  const int p = __builtin_amdgcn_update_dpp(0, __float_as_int(v), CTRL, 0xF, 0xF, true);
  return v + __int_as_float(p);
}

// ---- prep: w[u][j] = mu*iv, b[u] = logprop - 0.5*sum(mu^2*iv); zero d_out ----
__global__ void prep_kernel(const float* __restrict__ means,
                            const float* __restrict__ log_noise_var,
                            const float* __restrict__ log_prop,
                            float* __restrict__ w,
                            float* __restrict__ b,
                            float* __restrict__ out) {
  const int u = blockIdx.x;
  const int j = threadIdx.x;  // 128 threads
  const float iv = __expf(-log_noise_var[j]);
  const float mu = means[u * D + j];
  const float wv = mu * iv;
  w[u * D + j] = wv;
  float q = mu * wv;  // mu^2 * iv
#pragma unroll
  for (int off = 32; off; off >>= 1) q += __shfl_xor(q, off);
  __shared__ float red[2];
  if ((j & 63) == 0) red[j >> 6] = q;
  __syncthreads();
  if (j == 0) b[u] = log_prop[u] - 0.5f * (red[0] + red[1]);
  out[u * (D + 1) + j] = 0.f;
  if (j == 0) out[u * (D + 1) + D] = 0.f;
}

// ---- phase 1: responsibilities -> resp[n][10] (f32). No big LDS, high occ ----
__global__ void __launch_bounds__(256, 4) resp_kernel(
    const float* __restrict__ x, const int* __restrict__ cand,
    const float* __restrict__ wmat, const float* __restrict__ bvec,
    float* __restrict__ resp) {
  __shared__ float st[4][80];
  const int tid = threadIdx.x;
  const int lane = tid & 63;
  const int wid = tid >> 6;     // 4 waves
  const int g = lane >> 3;      // 8 spikes per wave
  const int l = lane & 7;       // 8 lanes per spike

  const int spike8 = (blockIdx.x * 4 + wid) * 8;
  const int spike = spike8 + g;

  // x fragment: dims q*32 + l*4 + i (contiguous 128B per q across 8 lanes)
  const float* xrow = x + (size_t)spike * D;
  float xv[16];
#pragma unroll
  for (int q = 0; q < 4; ++q) {
    const float4 t = *reinterpret_cast<const float4*>(xrow + q * 32 + l * 4);
    xv[4 * q + 0] = t.x; xv[4 * q + 1] = t.y;
    xv[4 * q + 2] = t.z; xv[4 * q + 3] = t.w;
  }

  int uc[KCAND];
#pragma unroll
  for (int k = 0; k < KCAND; ++k) uc[k] = cand[(size_t)spike * KCAND + k];

  float e[KCAND];
#pragma unroll
  for (int k = 0; k < KCAND; ++k) {
    const float* wrow = wmat + (size_t)uc[k] * D;
    float acc = 0.f;
#pragma unroll
    for (int q = 0; q < 4; ++q) {
      const float4 t = *reinterpret_cast<const float4*>(wrow + q * 32 + l * 4);
      acc = fmaf(xv[4 * q + 0], t.x, acc);
      acc = fmaf(xv[4 * q + 1], t.y, acc);
      acc = fmaf(xv[4 * q + 2], t.z, acc);
      acc = fmaf(xv[4 * q + 3], t.w, acc);
    }
    acc = dpp_add<0xB1>(acc);   // xor 1
    acc = dpp_add<0x4E>(acc);   // xor 2
    acc += __shfl_xor(acc, 4);  // xor 4
    e[k] = acc + bvec[uc[k]];
  }

  // softmax over [z_0..z_9, NOISE_LOGIT]
  float m = NOISE_LOGIT;
#pragma unroll
  for (int k = 0; k < KCAND; ++k) m = fmaxf(m, e[k]);
  float ssum = __expf(NOISE_LOGIT - m);
#pragma unroll
  for (int k = 0; k < KCAND; ++k) { e[k] = __expf(e[k] - m); ssum += e[k]; }
  const float rinv = 1.f / ssum;
#pragma unroll
  for (int k = 0; k < KCAND; ++k) e[k] *= rinv;

  // stage 80 resp values per wave through LDS, store coalesced
  if (l == 0) {
#pragma unroll
    for (int k = 0; k < KCAND; ++k) st[wid][g * KCAND + k] = e[k];
  }
  __syncthreads();
  const size_t rbase = (size_t)spike8 * KCAND;
  resp[rbase + lane] = st[wid][lane];
  if (lane < 16) resp[rbase + 64 + lane] = st[wid][64 + lane];
}

// ---- phase 2: scatter-add into LDS-privatized [256 x 65] tile ----
// bid&1 selects dim-half; native ds_add_f32 via unsafeAtomicAdd.
__global__ void __launch_bounds__(512, 4) scat_kernel(
    const float* __restrict__ x, const int* __restrict__ cand,
    const float* __restrict__ resp, float* __restrict__ out, int n) {
  extern __shared__ float tile[];  // UNITS * ST = 66560 B
  const int tid = threadIdx.x;
  for (int i = tid; i < UNITS * ST; i += 512) tile[i] = 0.f;
  __syncthreads();

  const int half = blockIdx.x & 1;   // 0: dims 0..63, 1: dims 64..127 + count
  const int sblk = blockIdx.x >> 1;  // 512 spike-slices
  const int lane = tid & 63;
  const int wid = tid >> 6;          // 8 waves
  const int ho = half * HD;

  const int spb = n >> 9;            // 256 spikes per block
  const int wsp = spb >> 3;          // 32 per wave
  const int base = sblk * spb + wid * wsp;
  const float* xo = x + ho;

  for (int it = 0; it < (wsp >> 3); ++it) {  // 4 iters of 8 spikes
    const int spike8 = base + it * 8;
    const size_t cb = (size_t)spike8 * KCAND;

    // cooperative loads: 80 (u,r) pairs + 8 x-row halves (256B coalesced)
    const int c0 = cand[cb + lane];
    const int c1 = (lane < 16) ? cand[cb + 64 + lane] : 0;
    const float r0 = resp[cb + lane];
    const float r1 = (lane < 16) ? resp[cb + 64 + lane] : 0.f;
    float xs[8];
#pragma unroll
    for (int s = 0; s < 8; ++s)
      xs[s] = xo[(size_t)(spike8 + s) * D + lane];

    // count column (half 1 only): per-lane native LDS atomics
    if (half) {
      unsafeAtomicAdd(&tile[c0 * ST + HD], r0);
      if (lane < 16) unsafeAtomicAdd(&tile[c1 * ST + HD], r1);
    }

    // scatter: one ds_add_f32 per (spike,cand); lanes = 64 consecutive dims
    // -> exactly 2 lanes/bank, conflict-free. (u,r) broadcast via v_readlane.
#pragma unroll
    for (int s = 0; s < 8; ++s) {
#pragma unroll
      for (int k = 0; k < KCAND; ++k) {
        const int j = s * KCAND + k;
        int u; float r;
        if (j < 64) {
          u = __builtin_amdgcn_readlane(c0, j);
          r = __int_as_float(__builtin_amdgcn_readlane(__float_as_int(r0), j));
        } else {
          u = __builtin_amdgcn_readlane(c1, j - 64);
          r = __int_as_float(__builtin_amdgcn_readlane(__float_as_int(r1), j - 64));
        }
        unsafeAtomicAdd(&tile[u * ST + lane], r * xs[s]);
      }
    }
  }

  __syncthreads();
  // flush: each wave owns 32 unit rows; coalesced global atomic bursts
  const int u0 = wid * 32;
  for (int u = u0; u < u0 + 32; ++u)
    unsafeAtomicAdd(&out[u * (D + 1) + ho + lane], tile[u * ST + lane]);
  if (half) {
    for (int u = tid; u < UNITS; u += 512)
      unsafeAtomicAdd(&out[u * (D + 1) + D], tile[u * ST + HD]);
  }
}

extern "C" void kernel_launch(void* const* d_in, const int* in_sizes, int n_in,
                              void* d_out, int out_size, void* d_ws, size_t ws_size,
                              hipStream_t stream) {
  const float* features = (const float*)d_in[0];
  const float* means    = (const float*)d_in[1];
  const float* lnv      = (const float*)d_in[2];
  const float* lprop    = (const float*)d_in[3];
  const int*   cand     = (const int*)d_in[4];
  float* out = (float*)d_out;

  // ws layout: w[256*128] | b[256] | resp[n*10]  (~5.4 MB total)
  float* w = (float*)d_ws;
  float* b = w + UNITS * D;
  float* resp = b + UNITS;

  const int n = in_sizes[0] / D;  // 131072

  prep_kernel<<<UNITS, D, 0, stream>>>(means, lnv, lprop, w, b, out);

  resp_kernel<<<n / 32, 256, 0, stream>>>(features, cand, w, b, resp);

  const int lds_bytes = UNITS * ST * sizeof(float);  // 66560
  hipFuncSetAttribute((const void*)scat_kernel,
                      hipFuncAttributeMaxDynamicSharedMemorySize, lds_bytes);
  scat_kernel<<<1024, 512, lds_bytes, stream>>>(features, cand, resp, out, n);
}

// Round 3
// 193.186 us; speedup vs baseline: 5.1573x; 5.1573x over previous
//
#include <hip/hip_runtime.h>

// Truncated E-step (round 3):
//   z_k = x . w[u_k] + b[u_k]  (w = mu*exp(-lnv), b = logprop - 0.5*mu'*iv*mu)
//   noise logit == NOISE_LOG_PROP by softmax shift-invariance.
// Pipeline: prep (w,b, zero gstats) -> resp (softmax resp -> ws)
//           -> scat (LDS tile, NATIVE ds_add_u32 fixed-point) -> finish.
// KEY FIX vs rounds 1/2: LDS f32 atomicAdd (both plain and unsafe) compiles
// to a ~208cy CAS loop on this toolchain (evidence: identical 884/888us for
// two different structures with equal atomic counts). Integer LDS atomics
// are always native. Accumulate in Q.17 fixed point; |sum| << 2^31/2^17.

#define UNITS 256
#define D 128
#define KCAND 10
#define NOISE_LOGIT (-2.0f)
#define HD 64                    // dims per scatter half-block
#define ST 65                    // LDS tile row stride (64 dims + count col)
#define SCALE 131072.0f          // 2^17
#define INV_SCALE (1.0f / 131072.0f)
#define GSTATS_ELEMS (UNITS * (D + 1))  // 33024

template <int CTRL>
__device__ __forceinline__ float dpp_add(float v) {
  // quad_perm lane-xor add: 0xB1 -> xor1, 0x4E -> xor2
  const int p = __builtin_amdgcn_update_dpp(0, __float_as_int(v), CTRL, 0xF, 0xF, true);
  return v + __int_as_float(p);
}

// ---- prep: w[u][j]=mu*iv, b[u]=logprop-0.5*sum(mu^2*iv); zero gstats ----
__global__ void prep_kernel(const float* __restrict__ means,
                            const float* __restrict__ log_noise_var,
                            const float* __restrict__ log_prop,
                            float* __restrict__ w,
                            float* __restrict__ b,
                            unsigned* __restrict__ gstats) {
  const int u = blockIdx.x;
  const int j = threadIdx.x;  // 128 threads
  const float iv = __expf(-log_noise_var[j]);
  const float mu = means[u * D + j];
  const float wv = mu * iv;
  w[u * D + j] = wv;
  float q = mu * wv;  // mu^2 * iv
#pragma unroll
  for (int off = 32; off; off >>= 1) q += __shfl_xor(q, off);
  __shared__ float red[2];
  if ((j & 63) == 0) red[j >> 6] = q;
  __syncthreads();
  if (j == 0) b[u] = log_prop[u] - 0.5f * (red[0] + red[1]);
  // zero the integer stats accumulator (ws is poisoned 0xAA every launch)
  for (int i = u * D + j; i < GSTATS_ELEMS; i += UNITS * D) gstats[i] = 0u;
}

// ---- phase 1: responsibilities -> resp[n][10] (f32) ----
__global__ void __launch_bounds__(256, 4) resp_kernel(
    const float* __restrict__ x, const int* __restrict__ cand,
    const float* __restrict__ wmat, const float* __restrict__ bvec,
    float* __restrict__ resp) {
  __shared__ float st[4][80];
  const int tid = threadIdx.x;
  const int lane = tid & 63;
  const int wid = tid >> 6;     // 4 waves
  const int g = lane >> 3;      // 8 spikes per wave
  const int l = lane & 7;       // 8 lanes per spike

  const int spike8 = (blockIdx.x * 4 + wid) * 8;
  const int spike = spike8 + g;

  const float* xrow = x + (size_t)spike * D;
  float xv[16];
#pragma unroll
  for (int q = 0; q < 4; ++q) {
    const float4 t = *reinterpret_cast<const float4*>(xrow + q * 32 + l * 4);
    xv[4 * q + 0] = t.x; xv[4 * q + 1] = t.y;
    xv[4 * q + 2] = t.z; xv[4 * q + 3] = t.w;
  }

  int uc[KCAND];
#pragma unroll
  for (int k = 0; k < KCAND; ++k) uc[k] = cand[(size_t)spike * KCAND + k];

  float e[KCAND];
#pragma unroll
  for (int k = 0; k < KCAND; ++k) {
    const float* wrow = wmat + (size_t)uc[k] * D;
    float acc = 0.f;
#pragma unroll
    for (int q = 0; q < 4; ++q) {
      const float4 t = *reinterpret_cast<const float4*>(wrow + q * 32 + l * 4);
      acc = fmaf(xv[4 * q + 0], t.x, acc);
      acc = fmaf(xv[4 * q + 1], t.y, acc);
      acc = fmaf(xv[4 * q + 2], t.z, acc);
      acc = fmaf(xv[4 * q + 3], t.w, acc);
    }
    acc = dpp_add<0xB1>(acc);   // xor 1
    acc = dpp_add<0x4E>(acc);   // xor 2
    acc += __shfl_xor(acc, 4);  // xor 4
    e[k] = acc + bvec[uc[k]];
  }

  float m = NOISE_LOGIT;
#pragma unroll
  for (int k = 0; k < KCAND; ++k) m = fmaxf(m, e[k]);
  float ssum = __expf(NOISE_LOGIT - m);
#pragma unroll
  for (int k = 0; k < KCAND; ++k) { e[k] = __expf(e[k] - m); ssum += e[k]; }
  const float rinv = 1.f / ssum;
#pragma unroll
  for (int k = 0; k < KCAND; ++k) e[k] *= rinv;

  if (l == 0) {
#pragma unroll
    for (int k = 0; k < KCAND; ++k) st[wid][g * KCAND + k] = e[k];
  }
  __syncthreads();
  const size_t rbase = (size_t)spike8 * KCAND;
  resp[rbase + lane] = st[wid][lane];
  if (lane < 16) resp[rbase + 64 + lane] = st[wid][64 + lane];
}

// ---- phase 2: scatter-add into LDS [256 x 65] u32 tile (Q.17 fixed point) ----
__global__ void __launch_bounds__(512, 4) scat_kernel(
    const float* __restrict__ x, const int* __restrict__ cand,
    const float* __restrict__ resp, unsigned* __restrict__ gstats, int n) {
  extern __shared__ unsigned tile[];  // UNITS * ST = 66560 B
  const int tid = threadIdx.x;
  for (int i = tid; i < UNITS * ST; i += 512) tile[i] = 0u;
  __syncthreads();

  const int half = blockIdx.x & 1;   // 0: dims 0..63, 1: dims 64..127 + count
  const int sblk = blockIdx.x >> 1;  // 256 spike-slices
  const int lane = tid & 63;
  const int wid = tid >> 6;          // 8 waves
  const int ho = half * HD;

  const int spb = n >> 8;            // 512 spikes per block
  const int wsp = spb >> 3;          // 64 per wave
  const int base = sblk * spb + wid * wsp;
  const float* xo = x + ho;

  for (int it = 0; it < (wsp >> 3); ++it) {  // 8 iters of 8 spikes
    const int spike8 = base + it * 8;
    const size_t cb = (size_t)spike8 * KCAND;

    // cooperative loads: 80 (u,r) pairs + 8 x-row halves (256B coalesced)
    const int c0 = cand[cb + lane];
    const int c1 = (lane < 16) ? cand[cb + 64 + lane] : 0;
    const float r0 = resp[cb + lane];
    const float r1 = (lane < 16) ? resp[cb + 64 + lane] : 0.f;
    float xs[8];
#pragma unroll
    for (int s = 0; s < 8; ++s)
      xs[s] = xo[(size_t)(spike8 + s) * D + lane] * SCALE;  // pre-scaled Q.17

    // count column (half 1 only): native per-lane ds_add_u32
    if (half) {
      atomicAdd(&tile[c0 * ST + HD], (unsigned)__float2int_rn(r0 * SCALE));
      if (lane < 16)
        atomicAdd(&tile[c1 * ST + HD], (unsigned)__float2int_rn(r1 * SCALE));
    }

    // scatter: one ds_add_u32 per (spike,cand); lanes = 64 consecutive dims
    // -> 2 lanes/bank, conflict-free. (u,r) broadcast via v_readlane (SGPR).
#pragma unroll
    for (int s = 0; s < 8; ++s) {
#pragma unroll
      for (int k = 0; k < KCAND; ++k) {
        const int j = s * KCAND + k;
        int u; float r;
        if (j < 64) {
          u = __builtin_amdgcn_readlane(c0, j);
          r = __int_as_float(__builtin_amdgcn_readlane(__float_as_int(r0), j));
        } else {
          u = __builtin_amdgcn_readlane(c1, j - 64);
          r = __int_as_float(__builtin_amdgcn_readlane(__float_as_int(r1), j - 64));
        }
        atomicAdd(&tile[u * ST + lane], (unsigned)__float2int_rn(r * xs[s]));
      }
    }
  }

  __syncthreads();
  // flush partial tile via native global_atomic_add_u32 (i32 accumulator)
  const int u0 = wid * 32;
  for (int u = u0; u < u0 + 32; ++u)
    atomicAdd(&gstats[u * (D + 1) + ho + lane], tile[u * ST + lane]);
  if (half) {
    for (int u = tid; u < UNITS; u += 512)
      atomicAdd(&gstats[u * (D + 1) + D], tile[u * ST + HD]);
  }
}

// ---- finish: Q.17 integer -> f32 output ----
__global__ void finish_kernel(const unsigned* __restrict__ gstats,
                              float* __restrict__ out) {
  const int i = blockIdx.x * 256 + threadIdx.x;
  if (i < GSTATS_ELEMS) out[i] = (float)(int)gstats[i] * INV_SCALE;
}

extern "C" void kernel_launch(void* const* d_in, const int* in_sizes, int n_in,
                              void* d_out, int out_size, void* d_ws, size_t ws_size,
                              hipStream_t stream) {
  const float* features = (const float*)d_in[0];
  const float* means    = (const float*)d_in[1];
  const float* lnv      = (const float*)d_in[2];
  const float* lprop    = (const float*)d_in[3];
  const int*   cand     = (const int*)d_in[4];
  float* out = (float*)d_out;

  // ws layout: w[256*128] f32 | b[256] f32 | resp[n*10] f32 | gstats[33024] u32
  float* w = (float*)d_ws;
  float* b = w + UNITS * D;
  float* resp = b + UNITS;
  const int n = in_sizes[0] / D;  // 131072
  unsigned* gstats = (unsigned*)(resp + (size_t)n * KCAND);

  prep_kernel<<<UNITS, D, 0, stream>>>(means, lnv, lprop, w, b, gstats);

  resp_kernel<<<n / 32, 256, 0, stream>>>(features, cand, w, b, resp);

  const int lds_bytes = UNITS * ST * sizeof(unsigned);  // 66560
  hipFuncSetAttribute((const void*)scat_kernel,
                      hipFuncAttributeMaxDynamicSharedMemorySize, lds_bytes);
  scat_kernel<<<512, 512, lds_bytes, stream>>>(features, cand, resp, gstats, n);

  finish_kernel<<<(GSTATS_ELEMS + 255) / 256, 256, 0, stream>>>(gstats, out);
}

// Round 5
// 171.662 us; speedup vs baseline: 5.8039x; 1.1254x over previous
//
#include <hip/hip_runtime.h>

// Truncated E-step (round 5 == round 4 resubmit; infra failure last round).
//   z_k = x . w[u_k] + b[u_k]  (w = mu*exp(-lnv), b = logprop - 0.5*mu'*iv*mu)
//   noise logit == NOISE_LOG_PROP by softmax shift-invariance.
// One pass over features: dots -> softmax -> LDS Q.17 scatter (native
// ds_add_u32; f32 LDS atomics are a ~208cy CAS loop on this toolchain —
// established rounds 1-3). Full [256][129] u32 tile per block (132KB LDS),
// flat-flushed via native global u32 atomics; finish converts to f32.

#define UNITS 256
#define D 128
#define KCAND 10
#define NOISE_LOGIT (-2.0f)
#define ST 129                   // u32 words per unit row (128 dims + count)
#define LDS_WORDS (UNITS * ST)   // 33024 -> 132096 B
#define SCALE 131072.0f          // 2^17
#define INV_SCALE (1.0f / 131072.0f)
#define GSTATS_ELEMS (UNITS * (D + 1))

template <int CTRL>
__device__ __forceinline__ float dpp_add(float v) {
  // quad_perm lane-xor add: 0xB1 -> xor1, 0x4E -> xor2
  const int p = __builtin_amdgcn_update_dpp(0, __float_as_int(v), CTRL, 0xF, 0xF, true);
  return v + __int_as_float(p);
}

// ---- prep: w[u][j]=mu*iv, b[u]=logprop-0.5*sum(mu^2*iv); zero gstats ----
__global__ void prep_kernel(const float* __restrict__ means,
                            const float* __restrict__ log_noise_var,
                            const float* __restrict__ log_prop,
                            float* __restrict__ w,
                            float* __restrict__ b,
                            unsigned* __restrict__ gstats) {
  const int u = blockIdx.x;
  const int j = threadIdx.x;  // 128 threads
  const float iv = __expf(-log_noise_var[j]);
  const float mu = means[u * D + j];
  const float wv = mu * iv;
  w[u * D + j] = wv;
  float q = mu * wv;  // mu^2 * iv
#pragma unroll
  for (int off = 32; off; off >>= 1) q += __shfl_xor(q, off);
  __shared__ float red[2];
  if ((j & 63) == 0) red[j >> 6] = q;
  __syncthreads();
  if (j == 0) b[u] = log_prop[u] - 0.5f * (red[0] + red[1]);
  for (int i = u * D + j; i < GSTATS_ELEMS; i += UNITS * D) gstats[i] = 0u;
}

// ---- fused: dots + softmax + LDS Q.17 scatter + flush ----
__global__ void __launch_bounds__(1024, 1) fused_kernel(
    const float* __restrict__ x, const int* __restrict__ cand,
    const float* __restrict__ wmat, const float* __restrict__ bvec,
    unsigned* __restrict__ gstats, int n) {
  extern __shared__ unsigned tile[];  // [UNITS][ST]
  const int tid = threadIdx.x;
  for (int i = tid; i < LDS_WORDS; i += 1024) tile[i] = 0u;
  __syncthreads();

  const int lane = tid & 63;
  const int wid = tid >> 6;   // 16 waves
  const int g = lane >> 3;    // spike slot (8 spikes per wave-iter)
  const int l = lane & 7;     // 8 lanes per spike, 16 dims each

  const int spb = n >> 8;     // 512 spikes per block
  const int wsp = spb >> 4;   // 32 per wave
  const int base = blockIdx.x * spb + wid * wsp;

  for (int it = 0; it < (wsp >> 3); ++it) {  // 4 iters of 8 spikes
    const int spike8 = base + it * 8;
    const int spike = spike8 + g;

    // ---- dot phase: x fragment, dims q*32 + l*4 + i ----
    const float* xrow = x + (size_t)spike * D;
    float xv[16];
#pragma unroll
    for (int q = 0; q < 4; ++q) {
      const float4 t = *reinterpret_cast<const float4*>(xrow + q * 32 + l * 4);
      xv[4 * q + 0] = t.x; xv[4 * q + 1] = t.y;
      xv[4 * q + 2] = t.z; xv[4 * q + 3] = t.w;
    }

    int uc[KCAND];
#pragma unroll
    for (int k = 0; k < KCAND; ++k) uc[k] = cand[(size_t)spike * KCAND + k];

    float e[KCAND];
#pragma unroll
    for (int k = 0; k < KCAND; ++k) {
      const float* wrow = wmat + (size_t)uc[k] * D;
      float acc = 0.f;
#pragma unroll
      for (int q = 0; q < 4; ++q) {
        const float4 t = *reinterpret_cast<const float4*>(wrow + q * 32 + l * 4);
        acc = fmaf(xv[4 * q + 0], t.x, acc);
        acc = fmaf(xv[4 * q + 1], t.y, acc);
        acc = fmaf(xv[4 * q + 2], t.z, acc);
        acc = fmaf(xv[4 * q + 3], t.w, acc);
      }
      acc = dpp_add<0xB1>(acc);   // xor 1
      acc = dpp_add<0x4E>(acc);   // xor 2
      acc += __shfl_xor(acc, 4);  // xor 4
      e[k] = acc + bvec[uc[k]];
    }

    // ---- softmax over [z_0..z_9, NOISE_LOGIT] (replicated in 8 lanes) ----
    float m = NOISE_LOGIT;
#pragma unroll
    for (int k = 0; k < KCAND; ++k) m = fmaxf(m, e[k]);
    float ssum = __expf(NOISE_LOGIT - m);
#pragma unroll
    for (int k = 0; k < KCAND; ++k) { e[k] = __expf(e[k] - m); ssum += e[k]; }
    const float rinv = 1.f / ssum;
#pragma unroll
    for (int k = 0; k < KCAND; ++k) e[k] *= rinv;

    // ---- count column: lane l -> cand l; lanes 0,1 also cands 8,9 ----
    {
      float rsel = e[0]; int usel = uc[0];
#pragma unroll
      for (int k = 1; k < 8; ++k) {
        const bool p = (l == k);
        rsel = p ? e[k] : rsel;
        usel = p ? uc[k] : usel;
      }
      atomicAdd(&tile[usel * ST + D], (unsigned)__float2int_rn(rsel * SCALE));
      const float rs2 = (l == 0) ? e[8] : e[9];
      const int us2 = (l == 0) ? uc[8] : uc[9];
      if (l < 2)
        atomicAdd(&tile[us2 * ST + D], (unsigned)__float2int_rn(rs2 * SCALE));
    }

    // ---- x in wave layout, pre-scaled to Q.17 (L1-hot reload) ----
    float xsa[8], xsb[8];
#pragma unroll
    for (int s = 0; s < 8; ++s) {
      const float* xr = x + (size_t)(spike8 + s) * D;
      xsa[s] = xr[lane] * SCALE;
      xsb[s] = xr[lane + 64] * SCALE;
    }

    // ---- scatter: 2 ds_add_u32 per (spike,cand); 64 consecutive dims per
    // instr -> 2 lanes/bank, conflict-free. (u,r) via v_readlane (SGPR). ----
#pragma unroll
    for (int s = 0; s < 8; ++s) {
#pragma unroll
      for (int k = 0; k < KCAND; ++k) {
        const int u = __builtin_amdgcn_readlane(uc[k], s * 8);
        const float r = __int_as_float(
            __builtin_amdgcn_readlane(__float_as_int(e[k]), s * 8));
        unsigned* rowp = &tile[u * ST];
        atomicAdd(rowp + lane, (unsigned)__float2int_rn(r * xsa[s]));
        atomicAdd(rowp + 64 + lane, (unsigned)__float2int_rn(r * xsb[s]));
      }
    }
  }

  __syncthreads();
  // ---- flush: tile layout == gstats layout (stride 129), flat copy ----
  for (int i = tid; i < LDS_WORDS; i += 1024)
    atomicAdd(&gstats[i], tile[i]);
}

// ---- finish: Q.17 integer -> f32 output ----
__global__ void finish_kernel(const unsigned* __restrict__ gstats,
                              float* __restrict__ out) {
  const int i = blockIdx.x * 256 + threadIdx.x;
  if (i < GSTATS_ELEMS) out[i] = (float)(int)gstats[i] * INV_SCALE;
}

extern "C" void kernel_launch(void* const* d_in, const int* in_sizes, int n_in,
                              void* d_out, int out_size, void* d_ws, size_t ws_size,
                              hipStream_t stream) {
  const float* features = (const float*)d_in[0];
  const float* means    = (const float*)d_in[1];
  const float* lnv      = (const float*)d_in[2];
  const float* lprop    = (const float*)d_in[3];
  const int*   cand     = (const int*)d_in[4];
  float* out = (float*)d_out;

  // ws layout: w[256*128] f32 | b[256] f32 | gstats[33024] u32
  float* w = (float*)d_ws;
  float* b = w + UNITS * D;
  unsigned* gstats = (unsigned*)(b + UNITS);

  const int n = in_sizes[0] / D;  // 131072

  prep_kernel<<<UNITS, D, 0, stream>>>(means, lnv, lprop, w, b, gstats);

  const int lds_bytes = LDS_WORDS * sizeof(unsigned);  // 132096
  hipFuncSetAttribute((const void*)fused_kernel,
                      hipFuncAttributeMaxDynamicSharedMemorySize, lds_bytes);
  fused_kernel<<<256, 1024, lds_bytes, stream>>>(features, cand, w, b, gstats, n);

  finish_kernel<<<(GSTATS_ELEMS + 255) / 256, 256, 0, stream>>>(gstats, out);
}